// Round 8
// baseline (108.686 us; speedup 1.0000x reference)
//
#include <hip/hip_runtime.h>
#include <math.h>

#define HH 256
#define WW 256
#define BB 8
#define MM 256
#define NN (HH * WW)
#define ROWS 2
#define BLKS_PER_B (HH / ROWS)            // 128 -> grid 1024 = 4 blocks/CU

#define EPSI 1e-6f
#define MAXD 362.03867196751236f
#define EPS_OVER_MAXD (1e-6f / 362.03867196751236f)

static __device__ __forceinline__ float asqrt(float x) {
    return __builtin_amdgcn_sqrtf(x);     // single v_sqrt_f32
}

// ws layout (u32 units):
//   [0..15]                  sums (float s0,s1 per batch)
//   [16 .. 16+2048)          gmin, INVERTED float bits (0 == +inf)
//   [2064 .. 2064+524288)    sc table: 1/(p^4 + EPS/MAXD) per (b, n)   (2 MB)
//   [526352 .. +4096)        gts: prescaled (gy*nfY, gx*nfX) per (b,m) (16 KB)
#define WS_GMIN 16
#define WS_SC   2064
#define WS_GTS  (WS_SC + BB * NN)

// ---------------------------------------------------------------------------
// prep: build sc table + prescaled GT (memory-bound, ~4 MB traffic)
// ---------------------------------------------------------------------------
__global__ __launch_bounds__(256) void whd_prep(
    const float* __restrict__ pm, const float* __restrict__ gt,
    const float* __restrict__ osz, float* __restrict__ sc,
    float2* __restrict__ gts)
{
    const int idx = blockIdx.x * 256 + threadIdx.x;   // 0 .. B*NN-1
    const float p  = pm[idx];
    const float p2 = p * p;
    sc[idx] = 1.0f / fmaf(p2, p2, EPS_OVER_MAXD);

    if (idx < BB * MM) {
        const int b = idx >> 8;
        const float nfY = osz[b * 2 + 0] * (1.0f / HH);
        const float nfX = osz[b * 2 + 1] * (1.0f / WW);
        const float2 g = ((const float2*)gt)[idx];
        gts[idx] = make_float2(g.x * nfY, g.y * nfX);
    }
}

// ---------------------------------------------------------------------------
// main: 2 rows per block; ALL in-loop reads are wave-uniform -> scalar pipe.
// ---------------------------------------------------------------------------
__global__ __launch_bounds__(256, 4) void whd_main(
    const float* __restrict__ pm, const float* __restrict__ osz,
    const float* __restrict__ sc, const float2* __restrict__ gts,
    float* __restrict__ sums, unsigned* __restrict__ gmin)
{
    __shared__ float swred[8];

    const int tid = threadIdx.x;
    const int blk = blockIdx.x;   // 0..127
    const int b   = blockIdx.y;

    const float nfY = osz[b * 2 + 0] * (1.0f / HH);
    const float nfX = osz[b * 2 + 1] * (1.0f / WW);
    const int   r0  = blk * ROWS;
    const float y0  = (float)r0 * nfY;
    const float y1  = y0 + nfY;
    const float x   = (float)tid * nfX;

    // own pixels (coalesced vector loads)
    const float p0 = pm[b * NN + r0 * WW + tid];
    const float p1 = pm[b * NN + (r0 + 1) * WW + tid];

    const float2* gb = gts + b * MM;          // uniform base

    // ---- Phase A: pixel col=tid, rows r0/r1; min_m d^2.
    // gb[m] is wave-uniform -> s_load; 4 independent fmin chains.
    float m00 = INFINITY, m01 = INFINITY;     // row0
    float m10 = INFINITY, m11 = INFINITY;     // row1
    #pragma unroll 8
    for (int m = 0; m < MM; m += 2) {
        const float2 ga = gb[m];
        const float2 gc = gb[m + 1];
        const float dxa = x - ga.y;
        const float dxc = x - gc.y;
        const float da2 = dxa * dxa;
        const float dc2 = dxc * dxc;
        const float dy0a = y0 - ga.x, dy1a = y1 - ga.x;
        const float dy0c = y0 - gc.x, dy1c = y1 - gc.x;
        m00 = fminf(m00, fmaf(dy0a, dy0a, da2));
        m10 = fminf(m10, fmaf(dy1a, dy1a, da2));
        m01 = fminf(m01, fmaf(dy0c, dy0c, dc2));
        m11 = fminf(m11, fmaf(dy1c, dy1c, dc2));
    }
    const float mind2r0 = fminf(m00, m01);
    const float mind2r1 = fminf(m10, m11);

    // ---- Phase B: thread owns m=tid; min over block's 512 px of
    // (sqrt(d2)+EPS)*sc.  sc reads are wave-uniform -> s_load.
    const float2 gm  = gb[tid];               // per-lane load (once)
    const float  dy0 = y0 - gm.x, dy1 = y1 - gm.x;
    const float  ey0 = dy0 * dy0,  ey1 = dy1 * dy1;
    const float* sc0p = sc + b * NN + r0 * WW;         // uniform bases
    const float* sc1p = sc0p + WW;

    float cm0 = INFINITY, cm1 = INFINITY;
    float dx  = 0.0f - gm.y;
    #pragma unroll 8
    for (int c = 0; c < WW; ++c) {
        const float s0 = sc0p[c];             // s_load (scalar pipe)
        const float s1 = sc1p[c];
        const float d0 = fmaf(dx, dx, ey0);
        const float d1 = fmaf(dx, dx, ey1);
        cm0 = fminf(cm0, (asqrt(d0) + EPSI) * s0);
        cm1 = fminf(cm1, (asqrt(d1) + EPSI) * s1);
        dx += nfX;
    }
    const float cmin = fminf(cm0, cm1);

    // ---- term1 partials (thread-exclusive pixels), one wave reduce
    float sum0 = p0 + p1;
    float sum1 = fmaf(p0, asqrt(mind2r0), p1 * asqrt(mind2r1));
    #pragma unroll
    for (int off = 32; off; off >>= 1) {
        sum0 += __shfl_down(sum0, off, 64);
        sum1 += __shfl_down(sum1, off, 64);
    }
    if ((tid & 63) == 0) { swred[(tid >> 6) * 2] = sum0; swred[(tid >> 6) * 2 + 1] = sum1; }
    __syncthreads();

    // fire-and-forget merges only — no fence, no counter, no waiting
    if (tid == 0) {
        const float s0 = (swred[0] + swred[2]) + (swred[4] + swred[6]);
        const float s1 = (swred[1] + swred[3]) + (swred[5] + swred[7]);
        atomicAdd(&sums[b * 2 + 0], s0);
        atomicAdd(&sums[b * 2 + 1], s1);
    }
    atomicMax(&gmin[b * MM + tid], ~__float_as_uint(cmin));
}

// ---------------------------------------------------------------------------
__global__ __launch_bounds__(256) void whd_final(const float* __restrict__ sums,
                                                 const unsigned* __restrict__ gmin,
                                                 float* __restrict__ out) {
    __shared__ float gred[4];
    const int tid = threadIdx.x;

    float gacc = 0.0f;
    #pragma unroll
    for (int q = 0; q < BB; ++q) {
        const float v = __uint_as_float(~gmin[q * MM + tid]);
        gacc += fminf(fmaxf(v, 0.0f), MAXD);
    }
    #pragma unroll
    for (int off = 32; off; off >>= 1) gacc += __shfl_down(gacc, off, 64);
    if ((tid & 63) == 0) gred[tid >> 6] = gacc;
    __syncthreads();
    if (tid == 0) {
        float t1 = 0.0f;
        #pragma unroll
        for (int q = 0; q < BB; ++q)
            t1 += sums[q * 2 + 1] / (sums[q * 2 + 0] + EPSI);
        const float g2 = (gred[0] + gred[1]) + (gred[2] + gred[3]);
        out[0] = t1 * (1.0f / BB) + g2 * (1.0f / (BB * MM));
    }
}

// ---------------------------------------------------------------------------
extern "C" void kernel_launch(void* const* d_in, const int* in_sizes, int n_in,
                              void* d_out, int out_size, void* d_ws, size_t ws_size,
                              hipStream_t stream) {
    const float* pm  = (const float*)d_in[0];   // [B, H, W]
    const float* gt  = (const float*)d_in[1];   // [B, M, 2]
    const float* osz = (const float*)d_in[2];   // [B, 2]
    float* out = (float*)d_out;

    unsigned* ws0  = (unsigned*)d_ws;
    float*    sums = (float*)ws0;
    unsigned* gmin = ws0 + WS_GMIN;
    float*    sct  = (float*)(ws0 + WS_SC);
    float2*   gts  = (float2*)(ws0 + WS_GTS);

    // zero-init sums + gmin only (0 == +inf in inverted representation)
    hipMemsetAsync(ws0, 0, (WS_GMIN + BB * MM) * sizeof(unsigned), stream);

    whd_prep<<<BB * NN / 256, 256, 0, stream>>>(pm, gt, osz, sct, gts);

    dim3 grid(BLKS_PER_B, BB);
    whd_main<<<grid, 256, 0, stream>>>(pm, osz, sct, gts, sums, gmin);

    whd_final<<<1, 256, 0, stream>>>(sums, gmin, out);
}